// Round 18
// baseline (955.738 us; speedup 1.0000x reference)
//
#include <hip/hip_runtime.h>
#include <hip/hip_bf16.h>

#define NB 4096
#define NS 32
#define NI 16
#define NH 32

typedef float f32x2 __attribute__((ext_vector_type(2)));

// Wave-local LDS write->read turnaround: drain lgkm, fence the compiler.
// R17 PROVED the drain is mandatory (drain-free raced intermittently:
// first launch OK, graph replay diverged 4.4e-2). Same-wave DS ordering
// is NOT architecturally guaranteed on gfx950.
__device__ __forceinline__ void fence() {
    __builtin_amdgcn_wave_barrier();
    asm volatile("s_waitcnt lgkmcnt(0)" ::: "memory");
    __builtin_amdgcn_wave_barrier();
}

// Cross-half sum via the compiler-known permlane builtin (hazard-safe, VALU).
__device__ __forceinline__ float xhsum(float x) {
    auto p = __builtin_amdgcn_permlane32_swap(
        (int)__float_as_uint(x), (int)__float_as_uint(x), false, false);
    return __uint_as_float((unsigned)p[0]) + __uint_as_float((unsigned)p[1]);
}

// Register-to-register lane gather (LDS pipe, but NO write/fence needed).
__device__ __forceinline__ float bperm(int byteidx, float v) {
    return __uint_as_float((unsigned)__builtin_amdgcn_ds_bpermute(
        byteidx, (int)__float_as_uint(v)));
}

__device__ __forceinline__ f32x2 pkfma(f32x2 a, f32x2 b, f32x2 c) {
    return __builtin_elementwise_fma(a, b, c);   // v_pk_fma_f32 on gfx950
}

// R18: stage-3 consumes h2 via 16 ds_bpermute gathers per element (h2 is
// register-resident after xhsum, dup in lanes r / r+32) — removes one
// write+fence+8-read LDS round-trip per ode_f call. Fences 3 -> 2.
// FP op order in stage 3 is reproduced bitwise (even/odd-k accumulators).
__global__ void __launch_bounds__(256)
__attribute__((amdgpu_waves_per_eu(2, 2)))
odernn_kernel(
    const float* __restrict__ x,    // (B,S,I)
    const float* __restrict__ t,    // (B,S)
    const float* __restrict__ gWih, // (96,16)
    const float* __restrict__ gWhh, // (96,32)
    const float* __restrict__ gbih, // (96)
    const float* __restrict__ gbhh, // (96)
    const float* __restrict__ oW1,  // (64,32)
    const float* __restrict__ ob1,  // (64)
    const float* __restrict__ oW2,  // (32,64)
    const float* __restrict__ ob2,  // (32)
    const float* __restrict__ oW3,  // (32,32)
    const float* __restrict__ ob3,  // (32)
    const float* __restrict__ fW1,  // (64,32)
    const float* __restrict__ fb1,  // (64)
    const float* __restrict__ fW2,  // (1,64)
    const float* __restrict__ fb2,  // (1)
    float* __restrict__ outp)       // (B,1)
{
    const int tid  = threadIdx.x;
    const int lane = tid & 63;
    const int wid  = tid >> 6;
    const int b0   = blockIdx.x * 8 + wid * 2;
    const int b1   = b0 + 1;
    const int r    = lane & 31;
    const int hf   = lane >> 5;

    __shared__ float sWr[48 * 32];
    __shared__ float sWz[48 * 32];
    __shared__ float sWnh[32 * 32];
    __shared__ float sWni[16 * 32];
    // Per-element buffer: Y region floats [0..63], H1 region floats [64..127]
    __shared__ __align__(16) float buf[4][2][128];

    for (int i = tid; i < 48 * 32; i += 256) {
        int c = i >> 5, r0 = i & 31;
        sWr[i] = (c < 16) ? gWih[r0 * 16 + c]        : gWhh[r0 * 32 + (c - 16)];
        sWz[i] = (c < 16) ? gWih[(32 + r0) * 16 + c] : gWhh[(32 + r0) * 32 + (c - 16)];
    }
    for (int i = tid; i < 32 * 32; i += 256) {
        int c = i >> 5, r0 = i & 31;
        sWnh[i] = gWhh[(64 + r0) * 32 + c];
    }
    for (int i = tid; i < 16 * 32; i += 256) {
        int c = i >> 5, r0 = i & 31;
        sWni[i] = gWih[(64 + r0) * 16 + c];
    }
    __syncthreads();

    float* bufw0 = buf[wid][0];
    float* bufw1 = buf[wid][1];
    const float4* bb0 = reinterpret_cast<const float4*>(bufw0);
    const float4* bb1 = reinterpret_cast<const float4*>(bufw1);

    // ------- ODE MLP weights -> NAMED per-lane registers (shared) ----
    f32x2 w1_0, w1_1, w1_2, w1_3, w1_4, w1_5, w1_6, w1_7,
          w1_8, w1_9, w1_10, w1_11, w1_12, w1_13, w1_14, w1_15;
    f32x2 w2_0, w2_1, w2_2, w2_3, w2_4, w2_5, w2_6, w2_7,
          w2_8, w2_9, w2_10, w2_11, w2_12, w2_13, w2_14, w2_15;
    float w3_0, w3_1, w3_2, w3_3, w3_4, w3_5, w3_6, w3_7,
          w3_8, w3_9, w3_10, w3_11, w3_12, w3_13, w3_14, w3_15;
    {
        const float4* p1 = reinterpret_cast<const float4*>(oW1) + lane * 8;
        float4 v;
#define LD2(i, dA, dB) { v = p1[i]; dA = f32x2{v.x, v.y}; dB = f32x2{v.z, v.w}; }
        LD2(0, w1_0,  w1_1)  LD2(1, w1_2,  w1_3)
        LD2(2, w1_4,  w1_5)  LD2(3, w1_6,  w1_7)
        LD2(4, w1_8,  w1_9)  LD2(5, w1_10, w1_11)
        LD2(6, w1_12, w1_13) LD2(7, w1_14, w1_15)
#undef LD2
        const float4* p2 = reinterpret_cast<const float4*>(oW2) + r * 16 + hf * 8;
#define LD2(i, dA, dB) { v = p2[i]; dA = f32x2{v.x, v.y}; dB = f32x2{v.z, v.w}; }
        LD2(0, w2_0,  w2_1)  LD2(1, w2_2,  w2_3)
        LD2(2, w2_4,  w2_5)  LD2(3, w2_6,  w2_7)
        LD2(4, w2_8,  w2_9)  LD2(5, w2_10, w2_11)
        LD2(6, w2_12, w2_13) LD2(7, w2_14, w2_15)
#undef LD2
        const float4* p3 = reinterpret_cast<const float4*>(oW3) + r * 8 + hf * 4;
#define LDS4(i, d0, d1, d2, d3) { v = p3[i]; d0 = v.x; d1 = v.y; d2 = v.z; d3 = v.w; }
        LDS4(0, w3_0,  w3_1,  w3_2,  w3_3)
        LDS4(1, w3_4,  w3_5,  w3_6,  w3_7)
        LDS4(2, w3_8,  w3_9,  w3_10, w3_11)
        LDS4(3, w3_12, w3_13, w3_14, w3_15)
#undef LDS4
    }
    const float b1r = ob1[lane];
    const float b2r = ob2[r];
    const float b3r = ob3[r];

    const float brr = gbih[r]      + gbhh[r];
    const float bzz = gbih[32 + r] + gbhh[32 + r];
    const float bin = gbih[64 + r];
    const float bhn = gbhh[64 + r];

    const float* wrp  = &sWr[(hf * 24) * 32 + r];
    const float* wzp  = &sWz[(hf * 24) * 32 + r];
    const float* wnhp = &sWnh[(hf * 16) * 32 + r];
    const float* wnip = &sWni[r];

    const int bp3 = hf << 6;   // byte index of h2[16*hf] for bpermute

    // --- ODE MLP, 2 elements, 2 fences (stage3 via bpermute) ---
    auto ode_f2 = [&](float y0, float y1, float& o0, float& o1) {
        bufw0[hf * 32 + r] = y0;           // Y region
        bufw1[hf * 32 + r] = y1;
        fence();
        // ---- stage 1, element A then B (compiler interleaves; writes hoist)
        f32x2 p0 = f32x2{b1r, 0.0f};
#define S1A(kk, wA, wB) { float4 c0 = bb0[kk]; \
        p0  = pkfma(wA, f32x2{c0.x, c0.y}, p0);  \
        p0  = pkfma(wB, f32x2{c0.z, c0.w}, p0); }
        S1A(0, w1_0,  w1_1)  S1A(1, w1_2,  w1_3)
        S1A(2, w1_4,  w1_5)  S1A(3, w1_6,  w1_7)
        S1A(4, w1_8,  w1_9)  S1A(5, w1_10, w1_11)
        S1A(6, w1_12, w1_13) S1A(7, w1_14, w1_15)
#undef S1A
        bufw0[64 + lane] = fmaxf(p0.x + p0.y, 0.0f);   // H1 region
        f32x2 p1a = f32x2{b1r, 0.0f};
#define S1B(kk, wA, wB) { float4 c1 = bb1[kk]; \
        p1a = pkfma(wA, f32x2{c1.x, c1.y}, p1a); \
        p1a = pkfma(wB, f32x2{c1.z, c1.w}, p1a); }
        S1B(0, w1_0,  w1_1)  S1B(1, w1_2,  w1_3)
        S1B(2, w1_4,  w1_5)  S1B(3, w1_6,  w1_7)
        S1B(4, w1_8,  w1_9)  S1B(5, w1_10, w1_11)
        S1B(6, w1_12, w1_13) S1B(7, w1_14, w1_15)
#undef S1B
        bufw1[64 + lane] = fmaxf(p1a.x + p1a.y, 0.0f);
        fence();
        // ---- stage 2 (reads H1 region, quads 16 + hf*8 + kk)
        f32x2 q0 = f32x2{0.0f, 0.0f}, q1 = f32x2{0.0f, 0.0f};
        const int o2 = 16 + hf * 8;
#define S2(kk, wA, wB) { float4 c0 = bb0[o2 + kk]; float4 c1 = bb1[o2 + kk]; \
        q0 = pkfma(wA, f32x2{c0.x, c0.y}, q0); \
        q0 = pkfma(wB, f32x2{c0.z, c0.w}, q0); \
        q1 = pkfma(wA, f32x2{c1.x, c1.y}, q1); \
        q1 = pkfma(wB, f32x2{c1.z, c1.w}, q1); }
        S2(0, w2_0,  w2_1)  S2(1, w2_2,  w2_3)
        S2(2, w2_4,  w2_5)  S2(3, w2_6,  w2_7)
        S2(4, w2_8,  w2_9)  S2(5, w2_10, w2_11)
        S2(6, w2_12, w2_13) S2(7, w2_14, w2_15)
#undef S2
        float a2_0 = fmaxf(xhsum(q0.x + q0.y) + b2r, 0.0f);
        float a2_1 = fmaxf(xhsum(q1.x + q1.y) + b2r, 0.0f);
        // ---- stage 3: gather h2 via bpermute (no LDS write, no fence).
        // FP order identical to R11: even-k acc + odd-k acc, ascending.
        float aE0 = 0.f, aO0 = 0.f, aE1 = 0.f, aO1 = 0.f;
#define S3P(s, w3s) { \
        float g0 = bperm(bp3 + 4 * (s), a2_0); \
        float g1 = bperm(bp3 + 4 * (s), a2_1); \
        if ((s) & 1) { aO0 = fmaf(w3s, g0, aO0); aO1 = fmaf(w3s, g1, aO1); } \
        else         { aE0 = fmaf(w3s, g0, aE0); aE1 = fmaf(w3s, g1, aE1); } }
        S3P(0,  w3_0)  S3P(1,  w3_1)  S3P(2,  w3_2)  S3P(3,  w3_3)
        S3P(4,  w3_4)  S3P(5,  w3_5)  S3P(6,  w3_6)  S3P(7,  w3_7)
        S3P(8,  w3_8)  S3P(9,  w3_9)  S3P(10, w3_10) S3P(11, w3_11)
        S3P(12, w3_12) S3P(13, w3_13) S3P(14, w3_14) S3P(15, w3_15)
#undef S3P
        o0 = xhsum(aE0 + aO0) + b3r;
        o1 = xhsum(aE1 + aO1) + b3r;
    };

    // ---------- time loop ----------
    float hv0 = 0.0f, hv1 = 0.0f;
    float outv0 = 0.0f, outv1 = 0.0f;

    #pragma unroll 1
    for (int s = 0; s < NS - 1; ++s) {
        const float* xrow0 = x + ((size_t)b0 * NS + s) * NI;
        const float* xrow1 = x + ((size_t)b1 * NS + s) * NI;
        if (hf == 0) {
            bufw0[16 + r] = hv0;
            bufw1[16 + r] = hv1;
        } else {
            bufw0[r & 15] = xrow0[r & 15];
            bufw1[r & 15] = xrow1[r & 15];
        }
        fence();

        float ar0 = 0.f, ar1 = 0.f, az0 = 0.f, az1 = 0.f;
        #pragma unroll
        for (int kk = 0; kk < 6; ++kk) {
            float4 c0 = bb0[hf*6 + kk];
            float4 c1 = bb1[hf*6 + kk];
            float w;
            w = wrp[(4*kk  )*32]; ar0 = fmaf(w, c0.x, ar0); ar1 = fmaf(w, c1.x, ar1);
            w = wrp[(4*kk+1)*32]; ar0 = fmaf(w, c0.y, ar0); ar1 = fmaf(w, c1.y, ar1);
            w = wrp[(4*kk+2)*32]; ar0 = fmaf(w, c0.z, ar0); ar1 = fmaf(w, c1.z, ar1);
            w = wrp[(4*kk+3)*32]; ar0 = fmaf(w, c0.w, ar0); ar1 = fmaf(w, c1.w, ar1);
            w = wzp[(4*kk  )*32]; az0 = fmaf(w, c0.x, az0); az1 = fmaf(w, c1.x, az1);
            w = wzp[(4*kk+1)*32]; az0 = fmaf(w, c0.y, az0); az1 = fmaf(w, c1.y, az1);
            w = wzp[(4*kk+2)*32]; az0 = fmaf(w, c0.z, az0); az1 = fmaf(w, c1.z, az1);
            w = wzp[(4*kk+3)*32]; az0 = fmaf(w, c0.w, az0); az1 = fmaf(w, c1.w, az1);
        }
        float in0 = 0.f, in1 = 0.f, hn0 = 0.f, hn1 = 0.f;
        #pragma unroll
        for (int kk = 0; kk < 4; ++kk) {
            float4 c0 = bb0[kk];
            float4 c1 = bb1[kk];
            float w;
            w = wnip[(4*kk  )*32]; in0 = fmaf(w, c0.x, in0); in1 = fmaf(w, c1.x, in1);
            w = wnip[(4*kk+1)*32]; in0 = fmaf(w, c0.y, in0); in1 = fmaf(w, c1.y, in1);
            w = wnip[(4*kk+2)*32]; in0 = fmaf(w, c0.z, in0); in1 = fmaf(w, c1.z, in1);
            w = wnip[(4*kk+3)*32]; in0 = fmaf(w, c0.w, in0); in1 = fmaf(w, c1.w, in1);
        }
        #pragma unroll
        for (int kk = 0; kk < 4; ++kk) {
            float4 c0 = bb0[4 + hf*4 + kk];
            float4 c1 = bb1[4 + hf*4 + kk];
            float w;
            w = wnhp[(4*kk  )*32]; hn0 = fmaf(w, c0.x, hn0); hn1 = fmaf(w, c1.x, hn1);
            w = wnhp[(4*kk+1)*32]; hn0 = fmaf(w, c0.y, hn0); hn1 = fmaf(w, c1.y, hn1);
            w = wnhp[(4*kk+2)*32]; hn0 = fmaf(w, c0.z, hn0); hn1 = fmaf(w, c1.z, hn1);
            w = wnhp[(4*kk+3)*32]; hn0 = fmaf(w, c0.w, hn0); hn1 = fmaf(w, c1.w, hn1);
        }
        ar0 = xhsum(ar0) + brr;  ar1 = xhsum(ar1) + brr;
        az0 = xhsum(az0) + bzz;  az1 = xhsum(az1) + bzz;
        hn0 = xhsum(hn0) + bhn;  hn1 = xhsum(hn1) + bhn;
        in0 += bin;              in1 += bin;

        float rg0 = 1.0f / (1.0f + __expf(-ar0));
        float rg1 = 1.0f / (1.0f + __expf(-ar1));
        float zg0 = 1.0f / (1.0f + __expf(-az0));
        float zg1 = 1.0f / (1.0f + __expf(-az1));
        float ng0 = tanhf(fmaf(rg0, hn0, in0));
        float ng1 = tanhf(fmaf(rg1, hn1, in1));
        outv0 = (1.0f - zg0) * ng0 + zg0 * hv0;
        outv1 = (1.0f - zg1) * ng1 + zg1 * hv1;

        hv0 = outv0;
        hv1 = outv1;
        if (s < NS - 2) {
            const float ddt0 = (t[(size_t)b0 * NS + s + 1] - t[(size_t)b0 * NS + s]) * 0.25f;
            const float ddt1 = (t[(size_t)b1 * NS + s + 1] - t[(size_t)b1 * NS + s]) * 0.25f;
            float hi0 = outv0, hi1 = outv1;
            #pragma unroll 1
            for (int sub = 0; sub < 4; ++sub) {
                float k1_0, k1_1, k2_0, k2_1, k3_0, k3_1,
                      k4_0, k4_1, k5_0, k5_1, k6_0, k6_1;
                ode_f2(hi0, hi1, k1_0, k1_1);
                ode_f2(fmaf(ddt0, 0.2f * k1_0, hi0),
                       fmaf(ddt1, 0.2f * k1_1, hi1), k2_0, k2_1);
                ode_f2(fmaf(ddt0, fmaf((float)(9.0/40.0), k2_0, (float)(3.0/40.0) * k1_0), hi0),
                       fmaf(ddt1, fmaf((float)(9.0/40.0), k2_1, (float)(3.0/40.0) * k1_1), hi1),
                       k3_0, k3_1);
                ode_f2(fmaf(ddt0, fmaf((float)(32.0/9.0), k3_0,
                                  fmaf(-(float)(56.0/15.0), k2_0, (float)(44.0/45.0) * k1_0)), hi0),
                       fmaf(ddt1, fmaf((float)(32.0/9.0), k3_1,
                                  fmaf(-(float)(56.0/15.0), k2_1, (float)(44.0/45.0) * k1_1)), hi1),
                       k4_0, k4_1);
                ode_f2(fmaf(ddt0, fmaf(-(float)(212.0/729.0), k4_0,
                                  fmaf((float)(64448.0/6561.0), k3_0,
                                  fmaf(-(float)(25360.0/2187.0), k2_0, (float)(19372.0/6561.0) * k1_0))), hi0),
                       fmaf(ddt1, fmaf(-(float)(212.0/729.0), k4_1,
                                  fmaf((float)(64448.0/6561.0), k3_1,
                                  fmaf(-(float)(25360.0/2187.0), k2_1, (float)(19372.0/6561.0) * k1_1))), hi1),
                       k5_0, k5_1);
                ode_f2(fmaf(ddt0, fmaf(-(float)(5103.0/18656.0), k5_0,
                                  fmaf((float)(49.0/176.0), k4_0,
                                  fmaf((float)(46732.0/5247.0), k3_0,
                                  fmaf(-(float)(355.0/33.0), k2_0, (float)(9017.0/3168.0) * k1_0)))), hi0),
                       fmaf(ddt1, fmaf(-(float)(5103.0/18656.0), k5_1,
                                  fmaf((float)(49.0/176.0), k4_1,
                                  fmaf((float)(46732.0/5247.0), k3_1,
                                  fmaf(-(float)(355.0/33.0), k2_1, (float)(9017.0/3168.0) * k1_1)))), hi1),
                       k6_0, k6_1);
                hi0 = fmaf(ddt0, fmaf((float)(11.0/84.0), k6_0,
                                 fmaf(-(float)(2187.0/6784.0), k5_0,
                                 fmaf((float)(125.0/192.0), k4_0,
                                 fmaf((float)(500.0/1113.0), k3_0, (float)(35.0/384.0) * k1_0)))), hi0);
                hi1 = fmaf(ddt1, fmaf((float)(11.0/84.0), k6_1,
                                 fmaf(-(float)(2187.0/6784.0), k5_1,
                                 fmaf((float)(125.0/192.0), k4_1,
                                 fmaf((float)(500.0/1113.0), k3_1, (float)(35.0/384.0) * k1_1)))), hi1);
            }
            hv0 = hi0;
            hv1 = hi1;
        }
    }

    // ---------- FC head: relu(out @ fW1.T + fb1) @ fW2.T + fb2 ----------
    bufw0[hf * 32 + r] = outv0;
    bufw1[hf * 32 + r] = outv1;
    fence();
    f32x2 acc0 = f32x2{fb1[lane], 0.0f};
    f32x2 acc1h = f32x2{fb1[lane], 0.0f};
    {
        const float4* fw = reinterpret_cast<const float4*>(fW1) + lane * 8;
        #pragma unroll
        for (int kk = 0; kk < 8; ++kk) {
            float4 wv = fw[kk];
            float4 c0 = bb0[kk];
            float4 c1 = bb1[kk];
            acc0  = pkfma(f32x2{wv.x, wv.y}, f32x2{c0.x, c0.y}, acc0);
            acc0  = pkfma(f32x2{wv.z, wv.w}, f32x2{c0.z, c0.w}, acc0);
            acc1h = pkfma(f32x2{wv.x, wv.y}, f32x2{c1.x, c1.y}, acc1h);
            acc1h = pkfma(f32x2{wv.z, wv.w}, f32x2{c1.z, c1.w}, acc1h);
        }
    }
    float fw2v = fW2[lane];
    float pa = fmaxf(acc0.x + acc0.y, 0.0f) * fw2v;
    float pb = fmaxf(acc1h.x + acc1h.y, 0.0f) * fw2v;
    #pragma unroll
    for (int m = 1; m < 64; m <<= 1) {
        pa += __shfl_xor(pa, m, 64);
        pb += __shfl_xor(pb, m, 64);
    }
    if (lane == 0) {
        float bias = fb2[0];
        outp[b0] = pa + bias;
        outp[b1] = pb + bias;
    }
}

extern "C" void kernel_launch(void* const* d_in, const int* in_sizes, int n_in,
                              void* d_out, int out_size, void* d_ws, size_t ws_size,
                              hipStream_t stream) {
    (void)in_sizes; (void)n_in; (void)d_ws; (void)ws_size; (void)out_size;
    odernn_kernel<<<dim3(NB / 8), dim3(256), 0, stream>>>(
        (const float*)d_in[0],  (const float*)d_in[1],
        (const float*)d_in[2],  (const float*)d_in[3],
        (const float*)d_in[4],  (const float*)d_in[5],
        (const float*)d_in[6],  (const float*)d_in[7],
        (const float*)d_in[8],  (const float*)d_in[9],
        (const float*)d_in[10], (const float*)d_in[11],
        (const float*)d_in[12], (const float*)d_in[13],
        (const float*)d_in[14], (const float*)d_in[15],
        (float*)d_out);
}

// Round 19
// 692.019 us; speedup vs baseline: 1.3811x; 1.3811x over previous
//
#include <hip/hip_runtime.h>
#include <hip/hip_bf16.h>

#define NB 4096
#define NS 32
#define NI 16
#define NH 32

typedef float f32x2 __attribute__((ext_vector_type(2)));

// Wave-local LDS write->read turnaround: drain lgkm, fence the compiler.
// R17 proved the drain is MANDATORY on gfx950 (drain-free raced on replay).
__device__ __forceinline__ void fence() {
    __builtin_amdgcn_wave_barrier();
    asm volatile("s_waitcnt lgkmcnt(0)" ::: "memory");
    __builtin_amdgcn_wave_barrier();
}

// Cross-half sum via the compiler-known permlane builtin (hazard-safe, VALU).
__device__ __forceinline__ float xhsum(float x) {
    auto p = __builtin_amdgcn_permlane32_swap(
        (int)__float_as_uint(x), (int)__float_as_uint(x), false, false);
    return __uint_as_float((unsigned)p[0]) + __uint_as_float((unsigned)p[1]);
}

__device__ __forceinline__ f32x2 pkfma(f32x2 a, f32x2 b, f32x2 c) {
    return __builtin_elementwise_fma(a, b, c);   // v_pk_fma_f32 on gfx950
}

// Best-known configuration (R11): 2 elems/wave ILP-2, named f32x2 weights,
// waves_per_eu(2,2) — the only clean allocation point (VGPR=120, no scratch).
// Ledger: R12 (fewer LDS reads) null; R13/R16 (occupancy attrs) null —
// unified reg bucket pins 2 waves/SIMD; R14 (blocks) null — grid caps TLP;
// R15 (ILP-4) and R18 (bpermute) regressed; R17 (no drain) races.
__global__ void __launch_bounds__(256)
__attribute__((amdgpu_waves_per_eu(2, 2)))
odernn_kernel(
    const float* __restrict__ x,    // (B,S,I)
    const float* __restrict__ t,    // (B,S)
    const float* __restrict__ gWih, // (96,16)
    const float* __restrict__ gWhh, // (96,32)
    const float* __restrict__ gbih, // (96)
    const float* __restrict__ gbhh, // (96)
    const float* __restrict__ oW1,  // (64,32)
    const float* __restrict__ ob1,  // (64)
    const float* __restrict__ oW2,  // (32,64)
    const float* __restrict__ ob2,  // (32)
    const float* __restrict__ oW3,  // (32,32)
    const float* __restrict__ ob3,  // (32)
    const float* __restrict__ fW1,  // (64,32)
    const float* __restrict__ fb1,  // (64)
    const float* __restrict__ fW2,  // (1,64)
    const float* __restrict__ fb2,  // (1)
    float* __restrict__ outp)       // (B,1)
{
    const int tid  = threadIdx.x;
    const int lane = tid & 63;
    const int wid  = tid >> 6;
    const int b0   = blockIdx.x * 8 + wid * 2;
    const int b1   = b0 + 1;
    const int r    = lane & 31;
    const int hf   = lane >> 5;

    __shared__ float sWr[48 * 32];
    __shared__ float sWz[48 * 32];
    __shared__ float sWnh[32 * 32];
    __shared__ float sWni[16 * 32];
    __shared__ __align__(16) float buf[4][2][64];

    for (int i = tid; i < 48 * 32; i += 256) {
        int c = i >> 5, r0 = i & 31;
        sWr[i] = (c < 16) ? gWih[r0 * 16 + c]        : gWhh[r0 * 32 + (c - 16)];
        sWz[i] = (c < 16) ? gWih[(32 + r0) * 16 + c] : gWhh[(32 + r0) * 32 + (c - 16)];
    }
    for (int i = tid; i < 32 * 32; i += 256) {
        int c = i >> 5, r0 = i & 31;
        sWnh[i] = gWhh[(64 + r0) * 32 + c];
    }
    for (int i = tid; i < 16 * 32; i += 256) {
        int c = i >> 5, r0 = i & 31;
        sWni[i] = gWih[(64 + r0) * 16 + c];
    }
    __syncthreads();

    float* bufw0 = buf[wid][0];
    float* bufw1 = buf[wid][1];
    const float4* bb0 = reinterpret_cast<const float4*>(bufw0);
    const float4* bb1 = reinterpret_cast<const float4*>(bufw1);

    // ------- ODE MLP weights -> NAMED per-lane f32x2 registers (shared) ----
    f32x2 w1_0, w1_1, w1_2, w1_3, w1_4, w1_5, w1_6, w1_7,
          w1_8, w1_9, w1_10, w1_11, w1_12, w1_13, w1_14, w1_15;
    f32x2 w2_0, w2_1, w2_2, w2_3, w2_4, w2_5, w2_6, w2_7,
          w2_8, w2_9, w2_10, w2_11, w2_12, w2_13, w2_14, w2_15;
    f32x2 w3_0, w3_1, w3_2, w3_3, w3_4, w3_5, w3_6, w3_7;
    {
        const float4* p1 = reinterpret_cast<const float4*>(oW1) + lane * 8;
        float4 v;
#define LD2(i, dA, dB) { v = p1[i]; dA = f32x2{v.x, v.y}; dB = f32x2{v.z, v.w}; }
        LD2(0, w1_0,  w1_1)  LD2(1, w1_2,  w1_3)
        LD2(2, w1_4,  w1_5)  LD2(3, w1_6,  w1_7)
        LD2(4, w1_8,  w1_9)  LD2(5, w1_10, w1_11)
        LD2(6, w1_12, w1_13) LD2(7, w1_14, w1_15)
#undef LD2
        const float4* p2 = reinterpret_cast<const float4*>(oW2) + r * 16 + hf * 8;
#define LD2(i, dA, dB) { v = p2[i]; dA = f32x2{v.x, v.y}; dB = f32x2{v.z, v.w}; }
        LD2(0, w2_0,  w2_1)  LD2(1, w2_2,  w2_3)
        LD2(2, w2_4,  w2_5)  LD2(3, w2_6,  w2_7)
        LD2(4, w2_8,  w2_9)  LD2(5, w2_10, w2_11)
        LD2(6, w2_12, w2_13) LD2(7, w2_14, w2_15)
#undef LD2
        const float4* p3 = reinterpret_cast<const float4*>(oW3) + r * 8 + hf * 4;
#define LD2(i, dA, dB) { v = p3[i]; dA = f32x2{v.x, v.y}; dB = f32x2{v.z, v.w}; }
        LD2(0, w3_0, w3_1)  LD2(1, w3_2, w3_3)
        LD2(2, w3_4, w3_5)  LD2(3, w3_6, w3_7)
#undef LD2
    }
    const float b1r = ob1[lane];
    const float b2r = ob2[r];
    const float b3r = ob3[r];

    const float brr = gbih[r]      + gbhh[r];
    const float bzz = gbih[32 + r] + gbhh[32 + r];
    const float bin = gbih[64 + r];
    const float bhn = gbhh[64 + r];

    const float* wrp  = &sWr[(hf * 24) * 32 + r];
    const float* wzp  = &sWz[(hf * 24) * 32 + r];
    const float* wnhp = &sWnh[(hf * 16) * 32 + r];
    const float* wnip = &sWni[r];

    // --- ODE MLP for BOTH elements; per-element math identical to R9 ---
    auto ode_f2 = [&](float y0, float y1, float& o0, float& o1) {
        bufw0[hf * 32 + r] = y0;
        bufw1[hf * 32 + r] = y1;
        fence();
        f32x2 p0 = f32x2{b1r, 0.0f}, p1a = f32x2{b1r, 0.0f};
#define S1(kk, wA, wB) { float4 c0 = bb0[kk]; float4 c1 = bb1[kk]; \
        p0  = pkfma(wA, f32x2{c0.x, c0.y}, p0);  \
        p0  = pkfma(wB, f32x2{c0.z, c0.w}, p0);  \
        p1a = pkfma(wA, f32x2{c1.x, c1.y}, p1a); \
        p1a = pkfma(wB, f32x2{c1.z, c1.w}, p1a); }
        S1(0, w1_0,  w1_1)  S1(1, w1_2,  w1_3)
        S1(2, w1_4,  w1_5)  S1(3, w1_6,  w1_7)
        S1(4, w1_8,  w1_9)  S1(5, w1_10, w1_11)
        S1(6, w1_12, w1_13) S1(7, w1_14, w1_15)
#undef S1
        float a1_0 = fmaxf(p0.x + p0.y, 0.0f);
        float a1_1 = fmaxf(p1a.x + p1a.y, 0.0f);
        bufw0[lane] = a1_0;
        bufw1[lane] = a1_1;
        fence();
        f32x2 q0 = f32x2{0.0f, 0.0f}, q1 = f32x2{0.0f, 0.0f};
        const int o2 = hf * 8;
#define S2(kk, wA, wB) { float4 c0 = bb0[o2 + kk]; float4 c1 = bb1[o2 + kk]; \
        q0 = pkfma(wA, f32x2{c0.x, c0.y}, q0); \
        q0 = pkfma(wB, f32x2{c0.z, c0.w}, q0); \
        q1 = pkfma(wA, f32x2{c1.x, c1.y}, q1); \
        q1 = pkfma(wB, f32x2{c1.z, c1.w}, q1); }
        S2(0, w2_0,  w2_1)  S2(1, w2_2,  w2_3)
        S2(2, w2_4,  w2_5)  S2(3, w2_6,  w2_7)
        S2(4, w2_8,  w2_9)  S2(5, w2_10, w2_11)
        S2(6, w2_12, w2_13) S2(7, w2_14, w2_15)
#undef S2
        float a2_0 = fmaxf(xhsum(q0.x + q0.y) + b2r, 0.0f);
        float a2_1 = fmaxf(xhsum(q1.x + q1.y) + b2r, 0.0f);
        bufw0[hf * 32 + r] = a2_0;
        bufw1[hf * 32 + r] = a2_1;
        fence();
        f32x2 s0 = f32x2{0.0f, 0.0f}, s1 = f32x2{0.0f, 0.0f};
        const int o3 = hf * 4;
#define S3(kk, wA, wB) { float4 c0 = bb0[o3 + kk]; float4 c1 = bb1[o3 + kk]; \
        s0 = pkfma(wA, f32x2{c0.x, c0.y}, s0); \
        s0 = pkfma(wB, f32x2{c0.z, c0.w}, s0); \
        s1 = pkfma(wA, f32x2{c1.x, c1.y}, s1); \
        s1 = pkfma(wB, f32x2{c1.z, c1.w}, s1); }
        S3(0, w3_0, w3_1)  S3(1, w3_2, w3_3)
        S3(2, w3_4, w3_5)  S3(3, w3_6, w3_7)
#undef S3
        o0 = xhsum(s0.x + s0.y) + b3r;
        o1 = xhsum(s1.x + s1.y) + b3r;
    };

    // ---------- time loop ----------
    float hv0 = 0.0f, hv1 = 0.0f;
    float outv0 = 0.0f, outv1 = 0.0f;

    #pragma unroll 1
    for (int s = 0; s < NS - 1; ++s) {
        const float* xrow0 = x + ((size_t)b0 * NS + s) * NI;
        const float* xrow1 = x + ((size_t)b1 * NS + s) * NI;
        if (hf == 0) {
            bufw0[16 + r] = hv0;
            bufw1[16 + r] = hv1;
        } else {
            bufw0[r & 15] = xrow0[r & 15];
            bufw1[r & 15] = xrow1[r & 15];
        }
        fence();

        float ar0 = 0.f, ar1 = 0.f, az0 = 0.f, az1 = 0.f;
        #pragma unroll
        for (int kk = 0; kk < 6; ++kk) {
            float4 c0 = bb0[hf*6 + kk];
            float4 c1 = bb1[hf*6 + kk];
            float w;
            w = wrp[(4*kk  )*32]; ar0 = fmaf(w, c0.x, ar0); ar1 = fmaf(w, c1.x, ar1);
            w = wrp[(4*kk+1)*32]; ar0 = fmaf(w, c0.y, ar0); ar1 = fmaf(w, c1.y, ar1);
            w = wrp[(4*kk+2)*32]; ar0 = fmaf(w, c0.z, ar0); ar1 = fmaf(w, c1.z, ar1);
            w = wrp[(4*kk+3)*32]; ar0 = fmaf(w, c0.w, ar0); ar1 = fmaf(w, c1.w, ar1);
            w = wzp[(4*kk  )*32]; az0 = fmaf(w, c0.x, az0); az1 = fmaf(w, c1.x, az1);
            w = wzp[(4*kk+1)*32]; az0 = fmaf(w, c0.y, az0); az1 = fmaf(w, c1.y, az1);
            w = wzp[(4*kk+2)*32]; az0 = fmaf(w, c0.z, az0); az1 = fmaf(w, c1.z, az1);
            w = wzp[(4*kk+3)*32]; az0 = fmaf(w, c0.w, az0); az1 = fmaf(w, c1.w, az1);
        }
        float in0 = 0.f, in1 = 0.f, hn0 = 0.f, hn1 = 0.f;
        #pragma unroll
        for (int kk = 0; kk < 4; ++kk) {
            float4 c0 = bb0[kk];
            float4 c1 = bb1[kk];
            float w;
            w = wnip[(4*kk  )*32]; in0 = fmaf(w, c0.x, in0); in1 = fmaf(w, c1.x, in1);
            w = wnip[(4*kk+1)*32]; in0 = fmaf(w, c0.y, in0); in1 = fmaf(w, c1.y, in1);
            w = wnip[(4*kk+2)*32]; in0 = fmaf(w, c0.z, in0); in1 = fmaf(w, c1.z, in1);
            w = wnip[(4*kk+3)*32]; in0 = fmaf(w, c0.w, in0); in1 = fmaf(w, c1.w, in1);
        }
        #pragma unroll
        for (int kk = 0; kk < 4; ++kk) {
            float4 c0 = bb0[4 + hf*4 + kk];
            float4 c1 = bb1[4 + hf*4 + kk];
            float w;
            w = wnhp[(4*kk  )*32]; hn0 = fmaf(w, c0.x, hn0); hn1 = fmaf(w, c1.x, hn1);
            w = wnhp[(4*kk+1)*32]; hn0 = fmaf(w, c0.y, hn0); hn1 = fmaf(w, c1.y, hn1);
            w = wnhp[(4*kk+2)*32]; hn0 = fmaf(w, c0.z, hn0); hn1 = fmaf(w, c1.z, hn1);
            w = wnhp[(4*kk+3)*32]; hn0 = fmaf(w, c0.w, hn0); hn1 = fmaf(w, c1.w, hn1);
        }
        ar0 = xhsum(ar0) + brr;  ar1 = xhsum(ar1) + brr;
        az0 = xhsum(az0) + bzz;  az1 = xhsum(az1) + bzz;
        hn0 = xhsum(hn0) + bhn;  hn1 = xhsum(hn1) + bhn;
        in0 += bin;              in1 += bin;

        float rg0 = 1.0f / (1.0f + __expf(-ar0));
        float rg1 = 1.0f / (1.0f + __expf(-ar1));
        float zg0 = 1.0f / (1.0f + __expf(-az0));
        float zg1 = 1.0f / (1.0f + __expf(-az1));
        float ng0 = tanhf(fmaf(rg0, hn0, in0));
        float ng1 = tanhf(fmaf(rg1, hn1, in1));
        outv0 = (1.0f - zg0) * ng0 + zg0 * hv0;
        outv1 = (1.0f - zg1) * ng1 + zg1 * hv1;

        hv0 = outv0;
        hv1 = outv1;
        if (s < NS - 2) {
            const float ddt0 = (t[(size_t)b0 * NS + s + 1] - t[(size_t)b0 * NS + s]) * 0.25f;
            const float ddt1 = (t[(size_t)b1 * NS + s + 1] - t[(size_t)b1 * NS + s]) * 0.25f;
            float hi0 = outv0, hi1 = outv1;
            #pragma unroll 1
            for (int sub = 0; sub < 4; ++sub) {
                float k1_0, k1_1, k2_0, k2_1, k3_0, k3_1,
                      k4_0, k4_1, k5_0, k5_1, k6_0, k6_1;
                ode_f2(hi0, hi1, k1_0, k1_1);
                ode_f2(fmaf(ddt0, 0.2f * k1_0, hi0),
                       fmaf(ddt1, 0.2f * k1_1, hi1), k2_0, k2_1);
                ode_f2(fmaf(ddt0, fmaf((float)(9.0/40.0), k2_0, (float)(3.0/40.0) * k1_0), hi0),
                       fmaf(ddt1, fmaf((float)(9.0/40.0), k2_1, (float)(3.0/40.0) * k1_1), hi1),
                       k3_0, k3_1);
                ode_f2(fmaf(ddt0, fmaf((float)(32.0/9.0), k3_0,
                                  fmaf(-(float)(56.0/15.0), k2_0, (float)(44.0/45.0) * k1_0)), hi0),
                       fmaf(ddt1, fmaf((float)(32.0/9.0), k3_1,
                                  fmaf(-(float)(56.0/15.0), k2_1, (float)(44.0/45.0) * k1_1)), hi1),
                       k4_0, k4_1);
                ode_f2(fmaf(ddt0, fmaf(-(float)(212.0/729.0), k4_0,
                                  fmaf((float)(64448.0/6561.0), k3_0,
                                  fmaf(-(float)(25360.0/2187.0), k2_0, (float)(19372.0/6561.0) * k1_0))), hi0),
                       fmaf(ddt1, fmaf(-(float)(212.0/729.0), k4_1,
                                  fmaf((float)(64448.0/6561.0), k3_1,
                                  fmaf(-(float)(25360.0/2187.0), k2_1, (float)(19372.0/6561.0) * k1_1))), hi1),
                       k5_0, k5_1);
                ode_f2(fmaf(ddt0, fmaf(-(float)(5103.0/18656.0), k5_0,
                                  fmaf((float)(49.0/176.0), k4_0,
                                  fmaf((float)(46732.0/5247.0), k3_0,
                                  fmaf(-(float)(355.0/33.0), k2_0, (float)(9017.0/3168.0) * k1_0)))), hi0),
                       fmaf(ddt1, fmaf(-(float)(5103.0/18656.0), k5_1,
                                  fmaf((float)(49.0/176.0), k4_1,
                                  fmaf((float)(46732.0/5247.0), k3_1,
                                  fmaf(-(float)(355.0/33.0), k2_1, (float)(9017.0/3168.0) * k1_1)))), hi1),
                       k6_0, k6_1);
                hi0 = fmaf(ddt0, fmaf((float)(11.0/84.0), k6_0,
                                 fmaf(-(float)(2187.0/6784.0), k5_0,
                                 fmaf((float)(125.0/192.0), k4_0,
                                 fmaf((float)(500.0/1113.0), k3_0, (float)(35.0/384.0) * k1_0)))), hi0);
                hi1 = fmaf(ddt1, fmaf((float)(11.0/84.0), k6_1,
                                 fmaf(-(float)(2187.0/6784.0), k5_1,
                                 fmaf((float)(125.0/192.0), k4_1,
                                 fmaf((float)(500.0/1113.0), k3_1, (float)(35.0/384.0) * k1_1)))), hi1);
            }
            hv0 = hi0;
            hv1 = hi1;
        }
    }

    // ---------- FC head: relu(out @ fW1.T + fb1) @ fW2.T + fb2 ----------
    bufw0[hf * 32 + r] = outv0;
    bufw1[hf * 32 + r] = outv1;
    fence();
    f32x2 acc0 = f32x2{fb1[lane], 0.0f};
    f32x2 acc1h = f32x2{fb1[lane], 0.0f};
    {
        const float4* fw = reinterpret_cast<const float4*>(fW1) + lane * 8;
        #pragma unroll
        for (int kk = 0; kk < 8; ++kk) {
            float4 wv = fw[kk];
            float4 c0 = bb0[kk];
            float4 c1 = bb1[kk];
            acc0  = pkfma(f32x2{wv.x, wv.y}, f32x2{c0.x, c0.y}, acc0);
            acc0  = pkfma(f32x2{wv.z, wv.w}, f32x2{c0.z, c0.w}, acc0);
            acc1h = pkfma(f32x2{wv.x, wv.y}, f32x2{c1.x, c1.y}, acc1h);
            acc1h = pkfma(f32x2{wv.z, wv.w}, f32x2{c1.z, c1.w}, acc1h);
        }
    }
    float fw2v = fW2[lane];
    float pa = fmaxf(acc0.x + acc0.y, 0.0f) * fw2v;
    float pb = fmaxf(acc1h.x + acc1h.y, 0.0f) * fw2v;
    #pragma unroll
    for (int m = 1; m < 64; m <<= 1) {
        pa += __shfl_xor(pa, m, 64);
        pb += __shfl_xor(pb, m, 64);
    }
    if (lane == 0) {
        float bias = fb2[0];
        outp[b0] = pa + bias;
        outp[b1] = pb + bias;
    }
}

extern "C" void kernel_launch(void* const* d_in, const int* in_sizes, int n_in,
                              void* d_out, int out_size, void* d_ws, size_t ws_size,
                              hipStream_t stream) {
    (void)in_sizes; (void)n_in; (void)d_ws; (void)ws_size; (void)out_size;
    odernn_kernel<<<dim3(NB / 8), dim3(256), 0, stream>>>(
        (const float*)d_in[0],  (const float*)d_in[1],
        (const float*)d_in[2],  (const float*)d_in[3],
        (const float*)d_in[4],  (const float*)d_in[5],
        (const float*)d_in[6],  (const float*)d_in[7],
        (const float*)d_in[8],  (const float*)d_in[9],
        (const float*)d_in[10], (const float*)d_in[11],
        (const float*)d_in[12], (const float*)d_in[13],
        (const float*)d_in[14], (const float*)d_in[15],
        (float*)d_out);
}